// Round 1
// 246.991 us; speedup vs baseline: 1.0685x; 1.0685x over previous
//
#include <hip/hip_runtime.h>
#include <cstdint>
#include <cstddef>

// ---------------------------------------------------------------------------
// MultiheadAttention (double-softmax), MI355X. B=4,S=1024,D=1024,H=16.
// Inputs FP32 (dict order), output FP32. r12:264.7 r13:267.6 r14:263.9 µs.
// r15: qkv/out_proj -> m97 structure. r14 counters: qkv MfmaUtil 12.7%,
// HBM 12.5%, VGPR 40 (launch_bounds-strangled) => structure/latency-bound,
// only 8 MFMA/wave between barrier drains. Fix: 128x128 tile (16 MFMA/wave
// per K-step), global_load_lds(16B) for bf16 operands, reg-staged cvt for
// fp32 A with prefetch under MFMA, launch_bounds(256,3).
//   K0 cvt4: Wo,Wq,Wk,Wv fp32->bf16 into d_out[0,8MB) (dead until ln)
//   K1 qkv : q,k -> [B,S,D] bf16 (q*0.125); v -> [B,H,dk,S] bf16
//   K2 attn: two-pass double softmax, no-max softmax1 (scores << 88)
//   K3 outp: 128x128 tiles, ctx @ Wo_bf^T + bo -> pre bf16
//   K4 ln  : LayerNorm(pre + Q)*g + b -> d_out f32 [0,16MB)
// ws (24 MB): qb[0,8) kb[8,16) vb[16,24); pre bf16 aliases [0,8) (qb dead).
// d_out u16 view: wo[0,1M) wq[1M,2M) wk[2M,3M) wv[3M,4M) ctx[4M,8M).
// ---------------------------------------------------------------------------

typedef unsigned short ushort_t;
typedef __attribute__((ext_vector_type(8))) short bf16x8;     // MFMA A/B frag
typedef __attribute__((ext_vector_type(8))) unsigned short us8;
typedef __attribute__((ext_vector_type(4))) unsigned short us4;
typedef __attribute__((ext_vector_type(4))) float f32x4;      // MFMA C/D frag

#define MFMA16(a, b, c) __builtin_amdgcn_mfma_f32_16x16x32_bf16((a), (b), (c), 0, 0, 0)

__device__ __forceinline__ float b2f(ushort_t u) {
  union { unsigned int i; float f; } x; x.i = ((unsigned int)u) << 16; return x.f;
}
__device__ __forceinline__ ushort_t f2b(float f) {
  union { unsigned int i; float f; } x; x.f = f;
  unsigned int r = (x.i + 0x7FFFu + ((x.i >> 16) & 1u)) >> 16;  // RNE
  return (ushort_t)r;
}
__device__ __forceinline__ us8 cvt8(float4 a, float4 b) {
  us8 r;
  r[0] = f2b(a.x); r[1] = f2b(a.y); r[2] = f2b(a.z); r[3] = f2b(a.w);
  r[4] = f2b(b.x); r[5] = f2b(b.y); r[6] = f2b(b.z); r[7] = f2b(b.w);
  return r;
}

// async global->LDS, 16B per lane; lds base must be wave-uniform.
__device__ __forceinline__ void gll16(const ushort_t* g, ushort_t* l) {
  __builtin_amdgcn_global_load_lds(
      (const __attribute__((address_space(1))) void*)g,
      (__attribute__((address_space(3))) void*)l, 16, 0, 0);
}

// ---------------------------------------------------------------------------
// K0: convert 4 weight matrices (1M fp32 elems each) to bf16.
// ---------------------------------------------------------------------------
__global__ __launch_bounds__(256, 8) void cvt4_kernel(
    const float* __restrict__ w0, const float* __restrict__ w1,
    const float* __restrict__ w2, const float* __restrict__ w3,
    ushort_t* __restrict__ dst) {
  const int which = blockIdx.y;
  const float* src = (which == 0) ? w0 : (which == 1) ? w1 : (which == 2) ? w2 : w3;
  const int i = (blockIdx.x * 256 + threadIdx.x) * 8;
  const float4 a = *(const float4*)(src + i);
  const float4 b = *(const float4*)(src + i + 4);
  *(us8*)(dst + (size_t)which * 1048576 + i) = cvt8(a, b);
}

// ---------------------------------------------------------------------------
// K1: Q/K/V projections. m97 structure: 128x128 tile, BK=32, 4 waves (2x2),
// 4x4 frags/wave. B (bf16) via global_load_lds; A (fp32) reg-staged with
// cvt at ds_write, next tile prefetched under MFMA. Grid (256,1,3).
// XCD swizzle: xcd = bid&7 owns m-tiles [xcd*4, xcd*4+4) x all 8 n-tiles
// (per-XCD: 2MB A fp32 + 2MB B bf16 = 4MB L2). z stride 256 ≡ 0 mod 8.
// ---------------------------------------------------------------------------
__global__ __launch_bounds__(256, 3) void qkv_proj_kernel(
    const float* __restrict__ Qin, const float* __restrict__ Kin,
    const float* __restrict__ Vin,
    const ushort_t* __restrict__ wq, const ushort_t* __restrict__ wk,
    const ushort_t* __restrict__ wv,
    const float* __restrict__ bq, const float* __restrict__ bk,
    const float* __restrict__ bv,
    ushort_t* __restrict__ qb, ushort_t* __restrict__ kb,
    ushort_t* __restrict__ vb) {
  __shared__ __align__(16) ushort_t Asl[128 * 32];
  __shared__ __align__(16) ushort_t Bsl[128 * 32];
  const float* A; const ushort_t* W; const float* bias; float scale;
  if (blockIdx.z == 0)      { A = Qin; W = wq; bias = bq; scale = 0.125f; }
  else if (blockIdx.z == 1) { A = Kin; W = wk; bias = bk; scale = 1.0f; }
  else                      { A = Vin; W = wv; bias = bv; scale = 1.0f; }
  const int l = blockIdx.x;
  const int xcd = l & 7, ii = l >> 3;
  const int m0 = (xcd * 4 + (ii >> 3)) * 128;
  const int n0 = (ii & 7) * 128;
  const int tid = threadIdx.x;
  const int wave = tid >> 6, lane = tid & 63;
  const int l15 = lane & 15, quad = lane >> 4;
  const int wr = wave >> 1, wc = wave & 1;

  // A staging: thread covers rows ra, ra+64; cols ca..ca+7 (fp32 -> bf16)
  const int ra = tid >> 2, ca = (tid & 3) * 8;
  const float* Ap0 = A + (size_t)(m0 + ra) * 1024 + ca;
  const float* Ap1 = A + (size_t)(m0 + ra + 64) * 1024 + ca;

  // B staging via gll: wave w, issue i covers dest rows (2w+i)*16..+15.
  const int rB0 = wave * 32 + (lane >> 2);
  const ushort_t* Bg0 = W + (size_t)(n0 + rB0) * 1024 + (lane & 3) * 8;
  const ushort_t* Bg1 = W + (size_t)(n0 + rB0 + 16) * 1024 + (lane & 3) * 8;
  ushort_t* Bl0 = Bsl + wave * 1024;        // (2w+0)*512 elems
  ushort_t* Bl1 = Bsl + wave * 1024 + 512;  // (2w+1)*512 elems

  float4 a00 = *(const float4*)(Ap0), a01 = *(const float4*)(Ap0 + 4);
  float4 a10 = *(const float4*)(Ap1), a11 = *(const float4*)(Ap1 + 4);

  f32x4 acc[4][4] = {};
  for (int k0 = 0; k0 < 1024; k0 += 32) {
    __syncthreads();                       // all waves done with prev tile
    *(us8*)(Asl + ra * 32 + ca) = cvt8(a00, a01);
    *(us8*)(Asl + (ra + 64) * 32 + ca) = cvt8(a10, a11);
    gll16(Bg0 + k0, Bl0);
    gll16(Bg1 + k0, Bl1);
    __syncthreads();                       // drains lgkm (A) + vmcnt (B)
    if (k0 + 32 < 1024) {                  // prefetch next A tile under MFMA
      a00 = *(const float4*)(Ap0 + k0 + 32); a01 = *(const float4*)(Ap0 + k0 + 36);
      a10 = *(const float4*)(Ap1 + k0 + 32); a11 = *(const float4*)(Ap1 + k0 + 36);
    }
    bf16x8 af[4], bfr[4];
#pragma unroll
    for (int s = 0; s < 4; ++s)
      af[s] = *(const bf16x8*)(Asl + (wr * 64 + s * 16 + l15) * 32 + quad * 8);
#pragma unroll
    for (int s = 0; s < 4; ++s)
      bfr[s] = *(const bf16x8*)(Bsl + (wc * 64 + s * 16 + l15) * 32 + quad * 8);
#pragma unroll
    for (int ms = 0; ms < 4; ++ms)
#pragma unroll
      for (int ns = 0; ns < 4; ++ns)
        acc[ms][ns] = MFMA16(af[ms], bfr[ns], acc[ms][ns]);
  }

  if (blockIdx.z != 2) {
    ushort_t* outp = (blockIdx.z == 0) ? qb : kb;
#pragma unroll
    for (int ns = 0; ns < 4; ++ns) {
      const int col = n0 + wc * 64 + ns * 16 + l15;
      const float bv_ = bias[col];
#pragma unroll
      for (int ms = 0; ms < 4; ++ms) {
        const int rowb = m0 + wr * 64 + ms * 16 + quad * 4;
#pragma unroll
        for (int r = 0; r < 4; ++r) {
          outp[(size_t)(rowb + r) * 1024 + col] =
              f2b((acc[ms][ns][r] + bv_) * scale);
        }
      }
    }
  } else {
    // V transposed: vb[((b*16+h)*64 + d)*1024 + s]
#pragma unroll
    for (int ns = 0; ns < 4; ++ns) {
      const int col = n0 + wc * 64 + ns * 16 + l15;
      const float bv_ = bias[col];
      const int h = col >> 6, d = col & 63;
#pragma unroll
      for (int ms = 0; ms < 4; ++ms) {
        const int i0 = m0 + wr * 64 + ms * 16 + quad * 4;
        const int b = i0 >> 10, s0 = i0 & 1023;
        us4 pack;
#pragma unroll
        for (int r = 0; r < 4; ++r) pack[r] = f2b(acc[ms][ns][r] + bv_);
        *(us4*)(vb + ((size_t)(b * 16 + h) * 64 + d) * 1024 + s0) = pack;
      }
    }
  }
}

// ---------------------------------------------------------------------------
// K2: attention, double softmax. 64-row Q tile, grid 1024 (flat, swizzled:
// xcd owns 8 bh values x all 16 q-tiles -> per-XCD K/V = 2MB in L2).
// Pass 1: Z1 = sum(exp(s)) only (no max). Pass 2: e2 = exp(exp(s)/Z1), PV.
// ---------------------------------------------------------------------------
__global__ __launch_bounds__(256, 4) void attn_kernel(
    const ushort_t* __restrict__ qb, const ushort_t* __restrict__ kb,
    const ushort_t* __restrict__ vb, ushort_t* __restrict__ ctx) {
  __shared__ __align__(16) ushort_t Qs[64 * 72];
  __shared__ __align__(16) ushort_t Ks[64 * 72];
  __shared__ __align__(16) ushort_t Vt[64 * 72];
  __shared__ __align__(16) ushort_t Ps[4][16 * 68];

  const int tid = threadIdx.x, wave = tid >> 6, lane = tid & 63;
  const int l15 = lane & 15, quad = lane >> 4;
  // XCD-aware swizzle
  const int l = blockIdx.x;
  const int xcd = l & 7, ii = l >> 3;
  const int bh = xcd * 8 + (ii >> 4);
  const int q0 = (ii & 15) * 64;
  const int b = bh >> 4, h = bh & 15;
  const ushort_t* qg = qb + ((size_t)b << 20) + h * 64;
  const ushort_t* kg = kb + ((size_t)b << 20) + h * 64;
  const ushort_t* vg = vb + ((size_t)bh << 16);   // [dk][S]

  const int kr0 = tid >> 3, kc0 = (tid & 7) * 8;
  const int kr1 = (tid + 256) >> 3, kc1 = kc0;

  *(us8*)(Qs + kr0 * 72 + kc0) = *(const us8*)(qg + (size_t)(q0 + kr0) * 1024 + kc0);
  *(us8*)(Qs + kr1 * 72 + kc1) = *(const us8*)(qg + (size_t)(q0 + kr1) * 1024 + kc1);

  // ---- pass 1: Z1 only ----
  float z1[4] = {0.f, 0.f, 0.f, 0.f};
  us8 rk0 = *(const us8*)(kg + (size_t)kr0 * 1024 + kc0);
  us8 rk1 = *(const us8*)(kg + (size_t)kr1 * 1024 + kc1);
  for (int kt = 0; kt < 16; ++kt) {
    __syncthreads();
    *(us8*)(Ks + kr0 * 72 + kc0) = rk0;
    *(us8*)(Ks + kr1 * 72 + kc1) = rk1;
    __syncthreads();
    if (kt < 15) {
      rk0 = *(const us8*)(kg + (size_t)((kt + 1) * 64 + kr0) * 1024 + kc0);
      rk1 = *(const us8*)(kg + (size_t)((kt + 1) * 64 + kr1) * 1024 + kc1);
    }
    f32x4 sc[4] = {};
#pragma unroll
    for (int kk = 0; kk < 2; ++kk) {
      const bf16x8 aq = *(const bf16x8*)(Qs + (wave * 16 + l15) * 72 + kk * 32 + quad * 8);
#pragma unroll
      for (int ns = 0; ns < 4; ++ns) {
        const bf16x8 bk_ = *(const bf16x8*)(Ks + (ns * 16 + l15) * 72 + kk * 32 + quad * 8);
        sc[ns] = MFMA16(aq, bk_, sc[ns]);
      }
    }
#pragma unroll
    for (int ns = 0; ns < 4; ++ns)
#pragma unroll
      for (int r = 0; r < 4; ++r) z1[r] += __expf(sc[ns][r]);
  }
  float iz1[4];
#pragma unroll
  for (int r = 0; r < 4; ++r) {
    float s = z1[r];
#pragma unroll
    for (int off = 1; off < 16; off <<= 1) s += __shfl_xor(s, off, 64);
    iz1[r] = 1.0f / s;
  }

  // ---- pass 2 ----
  f32x4 oac[4] = {};
  float z2[4] = {0.f, 0.f, 0.f, 0.f};
  rk0 = *(const us8*)(kg + (size_t)kr0 * 1024 + kc0);
  rk1 = *(const us8*)(kg + (size_t)kr1 * 1024 + kc1);
  us8 rv0 = *(const us8*)(vg + (size_t)kr0 * 1024 + kc0);
  us8 rv1 = *(const us8*)(vg + (size_t)kr1 * 1024 + kc1);
  for (int kt = 0; kt < 16; ++kt) {
    __syncthreads();
    *(us8*)(Ks + kr0 * 72 + kc0) = rk0;
    *(us8*)(Ks + kr1 * 72 + kc1) = rk1;
    *(us8*)(Vt + kr0 * 72 + kc0) = rv0;
    *(us8*)(Vt + kr1 * 72 + kc1) = rv1;
    __syncthreads();
    if (kt < 15) {
      rk0 = *(const us8*)(kg + (size_t)((kt + 1) * 64 + kr0) * 1024 + kc0);
      rk1 = *(const us8*)(kg + (size_t)((kt + 1) * 64 + kr1) * 1024 + kc1);
      rv0 = *(const us8*)(vg + (size_t)kr0 * 1024 + (kt + 1) * 64 + kc0);
      rv1 = *(const us8*)(vg + (size_t)kr1 * 1024 + (kt + 1) * 64 + kc1);
    }
    f32x4 sc[4] = {};
#pragma unroll
    for (int kk = 0; kk < 2; ++kk) {
      const bf16x8 aq = *(const bf16x8*)(Qs + (wave * 16 + l15) * 72 + kk * 32 + quad * 8);
#pragma unroll
      for (int ns = 0; ns < 4; ++ns) {
        const bf16x8 bk_ = *(const bf16x8*)(Ks + (ns * 16 + l15) * 72 + kk * 32 + quad * 8);
        sc[ns] = MFMA16(aq, bk_, sc[ns]);
      }
    }
#pragma unroll
    for (int ns = 0; ns < 4; ++ns)
#pragma unroll
      for (int r = 0; r < 4; ++r) {
        const float p1 = __expf(sc[ns][r]) * iz1[r];   // softmax1 (no max)
        const float e2 = __expf(p1);                   // softmax2 numerator
        z2[r] += e2;
        Ps[wave][(quad * 4 + r) * 68 + ns * 16 + l15] = f2b(e2);
      }
    __asm__ __volatile__("s_waitcnt lgkmcnt(0)" ::: "memory");  // Ps wave-private
#pragma unroll
    for (int kk = 0; kk < 2; ++kk) {
      const ushort_t* pp = &Ps[wave][l15 * 68 + kk * 32 + quad * 8];
      union { us4 hseg[2]; bf16x8 v; } u;
      u.hseg[0] = *(const us4*)pp;
      u.hseg[1] = *(const us4*)(pp + 4);
      const bf16x8 ap = u.v;
#pragma unroll
      for (int ns2 = 0; ns2 < 4; ++ns2) {
        const bf16x8 bv_ = *(const bf16x8*)(Vt + (ns2 * 16 + l15) * 72 + kk * 32 + quad * 8);
        oac[ns2] = MFMA16(ap, bv_, oac[ns2]);
      }
    }
  }

#pragma unroll
  for (int r = 0; r < 4; ++r) {
    float s = z2[r];
#pragma unroll
    for (int off = 1; off < 16; off <<= 1) s += __shfl_xor(s, off, 64);
    z2[r] = s;
  }
#pragma unroll
  for (int ns2 = 0; ns2 < 4; ++ns2) {
    const int d = ns2 * 16 + l15;
#pragma unroll
    for (int r = 0; r < 4; ++r) {
      const int s = q0 + wave * 16 + quad * 4 + r;
      ctx[((size_t)(b * 1024 + s)) * 1024 + h * 64 + d] = f2b(oac[ns2][r] / z2[r]);
    }
  }
}

// ---------------------------------------------------------------------------
// K3: pre = ctx @ Wo_bf^T + bo -> bf16. m97 structure: 128x128 tile, both
// operands bf16 via global_load_lds. Grid 256, swizzled like qkv.
// ---------------------------------------------------------------------------
__global__ __launch_bounds__(256, 3) void out_proj_kernel(
    const ushort_t* __restrict__ ctxp, const ushort_t* __restrict__ wo,
    const float* __restrict__ bo, ushort_t* __restrict__ pre) {
  __shared__ __align__(16) ushort_t Asl[128 * 32];
  __shared__ __align__(16) ushort_t Bsl[128 * 32];
  const int tid = threadIdx.x;
  const int wave = tid >> 6, lane = tid & 63;
  const int l15 = lane & 15, quad = lane >> 4;
  const int wr = wave >> 1, wc = wave & 1;
  const int l = blockIdx.x;
  const int xcd = l & 7, ii = l >> 3;
  const int m0 = (xcd * 4 + (ii >> 3)) * 128;
  const int n0 = (ii & 7) * 128;

  const int rr = wave * 32 + (lane >> 2);           // staging row (issue 0)
  const int cc = (lane & 3) * 8;
  const ushort_t* Ag0 = ctxp + (size_t)(m0 + rr) * 1024 + cc;
  const ushort_t* Ag1 = ctxp + (size_t)(m0 + rr + 16) * 1024 + cc;
  const ushort_t* Bg0 = wo + (size_t)(n0 + rr) * 1024 + cc;
  const ushort_t* Bg1 = wo + (size_t)(n0 + rr + 16) * 1024 + cc;
  ushort_t* Al0 = Asl + wave * 1024;
  ushort_t* Al1 = Asl + wave * 1024 + 512;
  ushort_t* Bl0 = Bsl + wave * 1024;
  ushort_t* Bl1 = Bsl + wave * 1024 + 512;

  f32x4 acc[4][4] = {};
  for (int k0 = 0; k0 < 1024; k0 += 32) {
    __syncthreads();
    gll16(Ag0 + k0, Al0);
    gll16(Ag1 + k0, Al1);
    gll16(Bg0 + k0, Bl0);
    gll16(Bg1 + k0, Bl1);
    __syncthreads();                       // drains vmcnt -> tile ready
    bf16x8 af[4], bfr[4];
#pragma unroll
    for (int s = 0; s < 4; ++s)
      af[s] = *(const bf16x8*)(Asl + (wr * 64 + s * 16 + l15) * 32 + quad * 8);
#pragma unroll
    for (int s = 0; s < 4; ++s)
      bfr[s] = *(const bf16x8*)(Bsl + (wc * 64 + s * 16 + l15) * 32 + quad * 8);
#pragma unroll
    for (int ms = 0; ms < 4; ++ms)
#pragma unroll
      for (int ns = 0; ns < 4; ++ns)
        acc[ms][ns] = MFMA16(af[ms], bfr[ns], acc[ms][ns]);
  }

#pragma unroll
  for (int ns = 0; ns < 4; ++ns) {
    const int col = n0 + wc * 64 + ns * 16 + l15;
    const float bv_ = bo[col];
#pragma unroll
    for (int ms = 0; ms < 4; ++ms) {
      const int rowb = m0 + wr * 64 + ms * 16 + quad * 4;
#pragma unroll
      for (int r = 0; r < 4; ++r) {
        pre[(size_t)(rowb + r) * 1024 + col] = f2b(acc[ms][ns][r] + bv_);
      }
    }
  }
}

// ---------------------------------------------------------------------------
// K4: out = LayerNorm(pre_bf16 + Q)*g + b -> f32. One block per row.
// ---------------------------------------------------------------------------
__global__ __launch_bounds__(256, 4) void ln_kernel(
    const ushort_t* __restrict__ pre, const float* __restrict__ Q,
    const float* __restrict__ g, const float* __restrict__ bta,
    float* __restrict__ out) {
  const int row = blockIdx.x;
  const int tid = threadIdx.x;
  const size_t base = (size_t)row * 1024 + tid * 4;
  const ushort4 p4 = *(const ushort4*)(pre + base);
  const float4 q4 = *(const float4*)(Q + base);
  float v[4] = {b2f(p4.x) + q4.x, b2f(p4.y) + q4.y,
                b2f(p4.z) + q4.z, b2f(p4.w) + q4.w};
  float s1 = v[0] + v[1] + v[2] + v[3];
  float s2 = v[0]*v[0] + v[1]*v[1] + v[2]*v[2] + v[3]*v[3];
#pragma unroll
  for (int off = 1; off < 64; off <<= 1) {
    s1 += __shfl_xor(s1, off, 64);
    s2 += __shfl_xor(s2, off, 64);
  }
  __shared__ float r1[4], r2[4];
  const int wave = tid >> 6, lane = tid & 63;
  if (lane == 0) { r1[wave] = s1; r2[wave] = s2; }
  __syncthreads();
  const float t1 = r1[0] + r1[1] + r1[2] + r1[3];
  const float t2 = r2[0] + r2[1] + r2[2] + r2[3];
  const float mu = t1 * (1.0f / 1024.0f);
  const float var = t2 * (1.0f / 1024.0f) - mu * mu;
  const float inv = rsqrtf(var + 1e-5f);
  const int c0 = tid * 4;
#pragma unroll
  for (int j = 0; j < 4; ++j) {
    const int c = c0 + j;
    out[(size_t)row * 1024 + c] = (v[j] - mu) * inv * g[c] + bta[c];
  }
}

// ---------------------------------------------------------------------------
extern "C" void kernel_launch(void* const* d_in, const int* in_sizes, int n_in,
                              void* d_out, int out_size, void* d_ws, size_t ws_size,
                              hipStream_t stream) {
  const float* Q  = (const float*)d_in[0];
  const float* K  = (const float*)d_in[1];
  const float* V  = (const float*)d_in[2];
  const float* Wq = (const float*)d_in[3];
  const float* bq = (const float*)d_in[4];
  const float* Wk = (const float*)d_in[5];
  const float* bk = (const float*)d_in[6];
  const float* Wv = (const float*)d_in[7];
  const float* bv = (const float*)d_in[8];
  const float* Wo = (const float*)d_in[9];
  const float* bo = (const float*)d_in[10];
  const float* lg = (const float*)d_in[11];
  const float* lb = (const float*)d_in[12];

  char* ws = (char*)d_ws;                       // 24 MB used
  ushort_t* qb  = (ushort_t*)(ws);                         // [B,S,D] bf16, scaled
  ushort_t* kb  = (ushort_t*)(ws + ((size_t)8  << 20));    // [B,S,D] bf16
  ushort_t* vb  = (ushort_t*)(ws + ((size_t)16 << 20));    // [B,H,dk,S] bf16
  ushort_t* pre = (ushort_t*)(ws);              // bf16, aliases qb (dead by K3)

  ushort_t* dptr  = (ushort_t*)d_out;           // u16 view of 16MB output
  ushort_t* wo_bf = dptr;                       // [0,1M) elems
  ushort_t* wq_bf = dptr + 1048576;             // [1M,2M)
  ushort_t* wk_bf = dptr + 2097152;             // [2M,3M)
  ushort_t* wv_bf = dptr + 3145728;             // [3M,4M)
  ushort_t* ctx   = dptr + 4194304;             // [4M,8M) = bytes [8MB,16MB)
  float*    out   = (float*)d_out;

  cvt4_kernel<<<dim3(512, 4), 256, 0, stream>>>(Wo, Wq, Wk, Wv, dptr);
  qkv_proj_kernel<<<dim3(256, 1, 3), 256, 0, stream>>>(Q, K, V, wq_bf, wk_bf, wv_bf,
                                                       bq, bk, bv, qb, kb, vb);
  attn_kernel<<<dim3(1024), 256, 0, stream>>>(qb, kb, vb, ctx);
  out_proj_kernel<<<dim3(256), 256, 0, stream>>>(ctx, wo_bf, bo, pre);
  ln_kernel<<<dim3(4096), 256, 0, stream>>>(pre, Q, lg, lb, out);
}

// Round 2
// 240.069 us; speedup vs baseline: 1.0993x; 1.0288x over previous
//
#include <hip/hip_runtime.h>
#include <cstdint>
#include <cstddef>

// ---------------------------------------------------------------------------
// MultiheadAttention (double-softmax), MI355X. B=4,S=1024,D=1024,H=16.
// Inputs FP32 (dict order), output FP32. r14:263.9 r15:247.0 µs.
// r16: 2-phase double-buffer for qkv/out_proj (T3 minimum recipe: stage t+1
// before compute t, ONE barrier/K-step; r15 had gll issued right before its
// own drain => zero overlap). out_proj 64x128 grid 512 (r15 grid 256 = 1
// block/CU, no co-residency). attn: exp2-folding (q pre-scaled by log2e =>
// v_exp_f32 only, no v_mul) + Q-frag hoist (kt-invariant).
//   K0 cvt4: Wo,Wq,Wk,Wv fp32->bf16 into d_out[0,8MB) (dead until ln)
//   K1 qkv : q,k -> [B,S,D] bf16 (q*0.125*log2e); v -> [B,H,dk,S] bf16
//   K2 attn: two-pass double softmax, no-max softmax1 (scores << 88)
//   K3 outp: 64x128 tiles, ctx @ Wo_bf^T + bo -> pre bf16
//   K4 ln  : LayerNorm(pre + Q)*g + b -> d_out f32 [0,16MB)
// ws (24 MB): qb[0,8) kb[8,16) vb[16,24); pre bf16 aliases [0,8) (qb dead).
// d_out u16 view: wo[0,1M) wq[1M,2M) wk[2M,3M) wv[3M,4M) ctx[4M,8M).
// ---------------------------------------------------------------------------

typedef unsigned short ushort_t;
typedef __attribute__((ext_vector_type(8))) short bf16x8;     // MFMA A/B frag
typedef __attribute__((ext_vector_type(8))) unsigned short us8;
typedef __attribute__((ext_vector_type(4))) unsigned short us4;
typedef __attribute__((ext_vector_type(4))) float f32x4;      // MFMA C/D frag

#define MFMA16(a, b, c) __builtin_amdgcn_mfma_f32_16x16x32_bf16((a), (b), (c), 0, 0, 0)
#define EXP2F(x) __builtin_amdgcn_exp2f(x)
#define LOG2E 1.4426950408889634f

__device__ __forceinline__ float b2f(ushort_t u) {
  union { unsigned int i; float f; } x; x.i = ((unsigned int)u) << 16; return x.f;
}
__device__ __forceinline__ ushort_t f2b(float f) {
  union { unsigned int i; float f; } x; x.f = f;
  unsigned int r = (x.i + 0x7FFFu + ((x.i >> 16) & 1u)) >> 16;  // RNE
  return (ushort_t)r;
}
__device__ __forceinline__ us8 cvt8(float4 a, float4 b) {
  us8 r;
  r[0] = f2b(a.x); r[1] = f2b(a.y); r[2] = f2b(a.z); r[3] = f2b(a.w);
  r[4] = f2b(b.x); r[5] = f2b(b.y); r[6] = f2b(b.z); r[7] = f2b(b.w);
  return r;
}

// async global->LDS, 16B per lane; lds base must be wave-uniform.
__device__ __forceinline__ void gll16(const ushort_t* g, ushort_t* l) {
  __builtin_amdgcn_global_load_lds(
      (const __attribute__((address_space(1))) void*)g,
      (__attribute__((address_space(3))) void*)l, 16, 0, 0);
}

// ---------------------------------------------------------------------------
// K0: convert 4 weight matrices (1M fp32 elems each) to bf16.
// ---------------------------------------------------------------------------
__global__ __launch_bounds__(256, 8) void cvt4_kernel(
    const float* __restrict__ w0, const float* __restrict__ w1,
    const float* __restrict__ w2, const float* __restrict__ w3,
    ushort_t* __restrict__ dst) {
  const int which = blockIdx.y;
  const float* src = (which == 0) ? w0 : (which == 1) ? w1 : (which == 2) ? w2 : w3;
  const int i = (blockIdx.x * 256 + threadIdx.x) * 8;
  const float4 a = *(const float4*)(src + i);
  const float4 b = *(const float4*)(src + i + 4);
  *(us8*)(dst + (size_t)which * 1048576 + i) = cvt8(a, b);
}

// ---------------------------------------------------------------------------
// K1: Q/K/V projections. 128x128 tile, BK=32, 2-phase LDS double-buffer:
// stage tile t+1 (gll B + cvt/ds_write A from ping-pong regs) BEFORE the
// MFMA on tile t; single barrier per K-step. Grid (256,1,3) = 3 blocks/CU.
// XCD swizzle: xcd = bid&7 owns m-tiles [xcd*4,+4) x all 8 n-tiles.
// ---------------------------------------------------------------------------
__global__ __launch_bounds__(256, 3) void qkv_proj_kernel(
    const float* __restrict__ Qin, const float* __restrict__ Kin,
    const float* __restrict__ Vin,
    const ushort_t* __restrict__ wq, const ushort_t* __restrict__ wk,
    const ushort_t* __restrict__ wv,
    const float* __restrict__ bq, const float* __restrict__ bk,
    const float* __restrict__ bv,
    ushort_t* __restrict__ qb, ushort_t* __restrict__ kb,
    ushort_t* __restrict__ vb) {
  __shared__ __align__(16) ushort_t Asl0[128 * 32];
  __shared__ __align__(16) ushort_t Asl1[128 * 32];
  __shared__ __align__(16) ushort_t Bsl0[128 * 32];
  __shared__ __align__(16) ushort_t Bsl1[128 * 32];
  const float* A; const ushort_t* W; const float* bias; float scale;
  if (blockIdx.z == 0)      { A = Qin; W = wq; bias = bq; scale = 0.125f * LOG2E; }
  else if (blockIdx.z == 1) { A = Kin; W = wk; bias = bk; scale = 1.0f; }
  else                      { A = Vin; W = wv; bias = bv; scale = 1.0f; }
  const int l = blockIdx.x;
  const int xcd = l & 7, ii = l >> 3;
  const int m0 = (xcd * 4 + (ii >> 3)) * 128;
  const int n0 = (ii & 7) * 128;
  const int tid = threadIdx.x;
  const int wave = tid >> 6, lane = tid & 63;
  const int l15 = lane & 15, quad = lane >> 4;
  const int wr = wave >> 1, wc = wave & 1;

  // A staging: thread covers rows ra, ra+64; cols ca..ca+7 (fp32 -> bf16)
  const int ra = tid >> 2, ca = (tid & 3) * 8;
  const float* Ap0 = A + (size_t)(m0 + ra) * 1024 + ca;
  const float* Ap1 = A + (size_t)(m0 + ra + 64) * 1024 + ca;

  // B staging via gll: wave w covers dest rows w*32..+15 and +16..+31.
  const ushort_t* Bg0 = W + (size_t)(n0 + wave * 32 + (lane >> 2)) * 1024 + (lane & 3) * 8;
  const ushort_t* Bg1 = W + (size_t)(n0 + wave * 32 + 16 + (lane >> 2)) * 1024 + (lane & 3) * 8;

  // prologue: tile0 -> buf0; preload tile1 into Y regs
  float4 xa0 = *(const float4*)(Ap0), xa1 = *(const float4*)(Ap0 + 4);
  float4 xa2 = *(const float4*)(Ap1), xa3 = *(const float4*)(Ap1 + 4);
  gll16(Bg0, Bsl0 + wave * 1024);
  gll16(Bg1, Bsl0 + wave * 1024 + 512);
  *(us8*)(Asl0 + ra * 32 + ca) = cvt8(xa0, xa1);
  *(us8*)(Asl0 + (ra + 64) * 32 + ca) = cvt8(xa2, xa3);
  float4 ya0 = *(const float4*)(Ap0 + 32), ya1 = *(const float4*)(Ap0 + 36);
  float4 ya2 = *(const float4*)(Ap1 + 32), ya3 = *(const float4*)(Ap1 + 36);
  __syncthreads();

  f32x4 acc[4][4] = {};
#define QKV_COMPUTE(ASL, BSL)                                                   \
  {                                                                             \
    bf16x8 af[4], bfr[4];                                                       \
    _Pragma("unroll") for (int s = 0; s < 4; ++s)                               \
        af[s] = *(const bf16x8*)((ASL) + (wr * 64 + s * 16 + l15) * 32 + quad * 8); \
    _Pragma("unroll") for (int s = 0; s < 4; ++s)                               \
        bfr[s] = *(const bf16x8*)((BSL) + (wc * 64 + s * 16 + l15) * 32 + quad * 8); \
    _Pragma("unroll") for (int ms = 0; ms < 4; ++ms)                            \
        _Pragma("unroll") for (int ns = 0; ns < 4; ++ns)                        \
            acc[ms][ns] = MFMA16(af[ms], bfr[ns], acc[ms][ns]);                 \
  }

  for (int k0 = 0; k0 < 1024; k0 += 64) {
    // even half: compute tile t (buf0); stage t+1 from Y -> buf1; load X <- t+2
    {
      gll16(Bg0 + k0 + 32, Bsl1 + wave * 1024);
      gll16(Bg1 + k0 + 32, Bsl1 + wave * 1024 + 512);
      *(us8*)(Asl1 + ra * 32 + ca) = cvt8(ya0, ya1);
      *(us8*)(Asl1 + (ra + 64) * 32 + ca) = cvt8(ya2, ya3);
    }
    if (k0 + 64 < 1024) {
      xa0 = *(const float4*)(Ap0 + k0 + 64); xa1 = *(const float4*)(Ap0 + k0 + 68);
      xa2 = *(const float4*)(Ap1 + k0 + 64); xa3 = *(const float4*)(Ap1 + k0 + 68);
    }
    QKV_COMPUTE(Asl0, Bsl0)
    __syncthreads();
    // odd half: compute tile t+1 (buf1); stage t+2 from X -> buf0; load Y <- t+3
    if (k0 + 64 < 1024) {
      gll16(Bg0 + k0 + 64, Bsl0 + wave * 1024);
      gll16(Bg1 + k0 + 64, Bsl0 + wave * 1024 + 512);
      *(us8*)(Asl0 + ra * 32 + ca) = cvt8(xa0, xa1);
      *(us8*)(Asl0 + (ra + 64) * 32 + ca) = cvt8(xa2, xa3);
      if (k0 + 96 < 1024) {
        ya0 = *(const float4*)(Ap0 + k0 + 96); ya1 = *(const float4*)(Ap0 + k0 + 100);
        ya2 = *(const float4*)(Ap1 + k0 + 96); ya3 = *(const float4*)(Ap1 + k0 + 100);
      }
    }
    QKV_COMPUTE(Asl1, Bsl1)
    __syncthreads();
  }
#undef QKV_COMPUTE

  if (blockIdx.z != 2) {
    ushort_t* outp = (blockIdx.z == 0) ? qb : kb;
#pragma unroll
    for (int ns = 0; ns < 4; ++ns) {
      const int col = n0 + wc * 64 + ns * 16 + l15;
      const float bv_ = bias[col];
#pragma unroll
      for (int ms = 0; ms < 4; ++ms) {
        const int rowb = m0 + wr * 64 + ms * 16 + quad * 4;
#pragma unroll
        for (int r = 0; r < 4; ++r) {
          outp[(size_t)(rowb + r) * 1024 + col] =
              f2b((acc[ms][ns][r] + bv_) * scale);
        }
      }
    }
  } else {
    // V transposed: vb[((b*16+h)*64 + d)*1024 + s]
#pragma unroll
    for (int ns = 0; ns < 4; ++ns) {
      const int col = n0 + wc * 64 + ns * 16 + l15;
      const float bv_ = bias[col];
      const int h = col >> 6, d = col & 63;
#pragma unroll
      for (int ms = 0; ms < 4; ++ms) {
        const int i0 = m0 + wr * 64 + ms * 16 + quad * 4;
        const int b = i0 >> 10, s0 = i0 & 1023;
        us4 pack;
#pragma unroll
        for (int r = 0; r < 4; ++r) pack[r] = f2b(acc[ms][ns][r] + bv_);
        *(us4*)(vb + ((size_t)(b * 16 + h) * 64 + d) * 1024 + s0) = pack;
      }
    }
  }
}

// ---------------------------------------------------------------------------
// K2: attention, double softmax. 64-row Q tile, grid 1024 (flat, swizzled:
// xcd owns 8 bh values x all 16 q-tiles -> per-XCD K/V = 2MB in L2).
// q pre-scaled by 0.125*log2e => exp(s) = exp2(sc) (bare v_exp_f32).
// Pass 1: Z1 = sum(exp2(sc)). Pass 2: e2 = exp2(exp2(sc)*log2e/Z1), PV.
// ---------------------------------------------------------------------------
__global__ __launch_bounds__(256, 4) void attn_kernel(
    const ushort_t* __restrict__ qb, const ushort_t* __restrict__ kb,
    const ushort_t* __restrict__ vb, ushort_t* __restrict__ ctx) {
  __shared__ __align__(16) ushort_t Qs[64 * 72];
  __shared__ __align__(16) ushort_t Ks[64 * 72];
  __shared__ __align__(16) ushort_t Vt[64 * 72];
  __shared__ __align__(16) ushort_t Ps[4][16 * 68];

  const int tid = threadIdx.x, wave = tid >> 6, lane = tid & 63;
  const int l15 = lane & 15, quad = lane >> 4;
  // XCD-aware swizzle
  const int l = blockIdx.x;
  const int xcd = l & 7, ii = l >> 3;
  const int bh = xcd * 8 + (ii >> 4);
  const int q0 = (ii & 15) * 64;
  const int b = bh >> 4, h = bh & 15;
  const ushort_t* qg = qb + ((size_t)b << 20) + h * 64;
  const ushort_t* kg = kb + ((size_t)b << 20) + h * 64;
  const ushort_t* vg = vb + ((size_t)bh << 16);   // [dk][S]

  const int kr0 = tid >> 3, kc0 = (tid & 7) * 8;
  const int kr1 = (tid + 256) >> 3, kc1 = kc0;

  *(us8*)(Qs + kr0 * 72 + kc0) = *(const us8*)(qg + (size_t)(q0 + kr0) * 1024 + kc0);
  *(us8*)(Qs + kr1 * 72 + kc1) = *(const us8*)(qg + (size_t)(q0 + kr1) * 1024 + kc1);
  __syncthreads();
  // Q fragments are kt-invariant: hoist to registers once.
  bf16x8 aqh[2];
  aqh[0] = *(const bf16x8*)(Qs + (wave * 16 + l15) * 72 + quad * 8);
  aqh[1] = *(const bf16x8*)(Qs + (wave * 16 + l15) * 72 + 32 + quad * 8);

  // ---- pass 1: Z1 only ----
  float z1[4] = {0.f, 0.f, 0.f, 0.f};
  us8 rk0 = *(const us8*)(kg + (size_t)kr0 * 1024 + kc0);
  us8 rk1 = *(const us8*)(kg + (size_t)kr1 * 1024 + kc1);
  for (int kt = 0; kt < 16; ++kt) {
    __syncthreads();
    *(us8*)(Ks + kr0 * 72 + kc0) = rk0;
    *(us8*)(Ks + kr1 * 72 + kc1) = rk1;
    __syncthreads();
    if (kt < 15) {
      rk0 = *(const us8*)(kg + (size_t)((kt + 1) * 64 + kr0) * 1024 + kc0);
      rk1 = *(const us8*)(kg + (size_t)((kt + 1) * 64 + kr1) * 1024 + kc1);
    }
    f32x4 sc[4] = {};
#pragma unroll
    for (int kk = 0; kk < 2; ++kk) {
#pragma unroll
      for (int ns = 0; ns < 4; ++ns) {
        const bf16x8 bk_ = *(const bf16x8*)(Ks + (ns * 16 + l15) * 72 + kk * 32 + quad * 8);
        sc[ns] = MFMA16(aqh[kk], bk_, sc[ns]);
      }
    }
#pragma unroll
    for (int ns = 0; ns < 4; ++ns)
#pragma unroll
      for (int r = 0; r < 4; ++r) z1[r] += EXP2F(sc[ns][r]);
  }
  float iz1[4];
#pragma unroll
  for (int r = 0; r < 4; ++r) {
    float s = z1[r];
#pragma unroll
    for (int off = 1; off < 16; off <<= 1) s += __shfl_xor(s, off, 64);
    iz1[r] = LOG2E / s;    // log2e folded: e2 = exp2(exp2(sc) * iz1)
  }

  // ---- pass 2 ----
  f32x4 oac[4] = {};
  float z2[4] = {0.f, 0.f, 0.f, 0.f};
  rk0 = *(const us8*)(kg + (size_t)kr0 * 1024 + kc0);
  rk1 = *(const us8*)(kg + (size_t)kr1 * 1024 + kc1);
  us8 rv0 = *(const us8*)(vg + (size_t)kr0 * 1024 + kc0);
  us8 rv1 = *(const us8*)(vg + (size_t)kr1 * 1024 + kc1);
  for (int kt = 0; kt < 16; ++kt) {
    __syncthreads();
    *(us8*)(Ks + kr0 * 72 + kc0) = rk0;
    *(us8*)(Ks + kr1 * 72 + kc1) = rk1;
    *(us8*)(Vt + kr0 * 72 + kc0) = rv0;
    *(us8*)(Vt + kr1 * 72 + kc1) = rv1;
    __syncthreads();
    if (kt < 15) {
      rk0 = *(const us8*)(kg + (size_t)((kt + 1) * 64 + kr0) * 1024 + kc0);
      rk1 = *(const us8*)(kg + (size_t)((kt + 1) * 64 + kr1) * 1024 + kc1);
      rv0 = *(const us8*)(vg + (size_t)kr0 * 1024 + (kt + 1) * 64 + kc0);
      rv1 = *(const us8*)(vg + (size_t)kr1 * 1024 + (kt + 1) * 64 + kc1);
    }
    f32x4 sc[4] = {};
#pragma unroll
    for (int kk = 0; kk < 2; ++kk) {
#pragma unroll
      for (int ns = 0; ns < 4; ++ns) {
        const bf16x8 bk_ = *(const bf16x8*)(Ks + (ns * 16 + l15) * 72 + kk * 32 + quad * 8);
        sc[ns] = MFMA16(aqh[kk], bk_, sc[ns]);
      }
    }
#pragma unroll
    for (int ns = 0; ns < 4; ++ns)
#pragma unroll
      for (int r = 0; r < 4; ++r) {
        const float p1 = EXP2F(sc[ns][r]) * iz1[r];    // softmax1 * log2e
        const float e2 = EXP2F(p1);                    // softmax2 numerator
        z2[r] += e2;
        Ps[wave][(quad * 4 + r) * 68 + ns * 16 + l15] = f2b(e2);
      }
    __asm__ __volatile__("s_waitcnt lgkmcnt(0)" ::: "memory");  // Ps wave-private
#pragma unroll
    for (int kk = 0; kk < 2; ++kk) {
      const ushort_t* pp = &Ps[wave][l15 * 68 + kk * 32 + quad * 8];
      union { us4 hseg[2]; bf16x8 v; } u;
      u.hseg[0] = *(const us4*)pp;
      u.hseg[1] = *(const us4*)(pp + 4);
      const bf16x8 ap = u.v;
#pragma unroll
      for (int ns2 = 0; ns2 < 4; ++ns2) {
        const bf16x8 bv_ = *(const bf16x8*)(Vt + (ns2 * 16 + l15) * 72 + kk * 32 + quad * 8);
        oac[ns2] = MFMA16(ap, bv_, oac[ns2]);
      }
    }
  }

#pragma unroll
  for (int r = 0; r < 4; ++r) {
    float s = z2[r];
#pragma unroll
    for (int off = 1; off < 16; off <<= 1) s += __shfl_xor(s, off, 64);
    z2[r] = s;
  }
#pragma unroll
  for (int ns2 = 0; ns2 < 4; ++ns2) {
    const int d = ns2 * 16 + l15;
#pragma unroll
    for (int r = 0; r < 4; ++r) {
      const int s = q0 + wave * 16 + quad * 4 + r;
      ctx[((size_t)(b * 1024 + s)) * 1024 + h * 64 + d] = f2b(oac[ns2][r] / z2[r]);
    }
  }
}

// ---------------------------------------------------------------------------
// K3: pre = ctx @ Wo_bf^T + bo -> bf16. 64x128 tiles, grid 512 (2 blocks/CU),
// 2-phase gll double-buffer, single barrier per K-step. Waves 2x2 over
// 64x128 -> per-wave 32x64, acc[2][4].
// ---------------------------------------------------------------------------
__global__ __launch_bounds__(256, 4) void out_proj_kernel(
    const ushort_t* __restrict__ ctxp, const ushort_t* __restrict__ wo,
    const float* __restrict__ bo, ushort_t* __restrict__ pre) {
  __shared__ __align__(16) ushort_t Asl0[64 * 32];
  __shared__ __align__(16) ushort_t Asl1[64 * 32];
  __shared__ __align__(16) ushort_t Bsl0[128 * 32];
  __shared__ __align__(16) ushort_t Bsl1[128 * 32];
  const int tid = threadIdx.x;
  const int wave = tid >> 6, lane = tid & 63;
  const int l15 = lane & 15, quad = lane >> 4;
  const int wr = wave >> 1, wc = wave & 1;
  const int l = blockIdx.x;
  const int xcd = l & 7, ii = l >> 3;        // 64 blocks per xcd
  const int m0 = (xcd * 8 + (ii >> 3)) * 64;
  const int n0 = (ii & 7) * 128;

  // A: wave w covers rows w*16..+15 (one gll); B: rows w*32..+31 (two gll).
  const ushort_t* Ag = ctxp + (size_t)(m0 + wave * 16 + (lane >> 2)) * 1024 + (lane & 3) * 8;
  const ushort_t* Bg0 = wo + (size_t)(n0 + wave * 32 + (lane >> 2)) * 1024 + (lane & 3) * 8;
  const ushort_t* Bg1 = wo + (size_t)(n0 + wave * 32 + 16 + (lane >> 2)) * 1024 + (lane & 3) * 8;

  // prologue: tile0 -> buf0
  gll16(Ag, Asl0 + wave * 512);
  gll16(Bg0, Bsl0 + wave * 1024);
  gll16(Bg1, Bsl0 + wave * 1024 + 512);
  __syncthreads();

  f32x4 acc[2][4] = {};
#define OUTP_COMPUTE(ASL, BSL)                                                  \
  {                                                                             \
    bf16x8 af[2], bfr[4];                                                       \
    _Pragma("unroll") for (int s = 0; s < 2; ++s)                               \
        af[s] = *(const bf16x8*)((ASL) + (wr * 32 + s * 16 + l15) * 32 + quad * 8); \
    _Pragma("unroll") for (int s = 0; s < 4; ++s)                               \
        bfr[s] = *(const bf16x8*)((BSL) + (wc * 64 + s * 16 + l15) * 32 + quad * 8); \
    _Pragma("unroll") for (int ms = 0; ms < 2; ++ms)                            \
        _Pragma("unroll") for (int ns = 0; ns < 4; ++ns)                        \
            acc[ms][ns] = MFMA16(af[ms], bfr[ns], acc[ms][ns]);                 \
  }

  for (int k0 = 0; k0 < 1024; k0 += 64) {
    // even half: compute buf0 (tile t), stage t+1 -> buf1
    {
      gll16(Ag + k0 + 32, Asl1 + wave * 512);
      gll16(Bg0 + k0 + 32, Bsl1 + wave * 1024);
      gll16(Bg1 + k0 + 32, Bsl1 + wave * 1024 + 512);
    }
    OUTP_COMPUTE(Asl0, Bsl0)
    __syncthreads();
    // odd half: compute buf1 (tile t+1), stage t+2 -> buf0
    if (k0 + 64 < 1024) {
      gll16(Ag + k0 + 64, Asl0 + wave * 512);
      gll16(Bg0 + k0 + 64, Bsl0 + wave * 1024);
      gll16(Bg1 + k0 + 64, Bsl0 + wave * 1024 + 512);
    }
    OUTP_COMPUTE(Asl1, Bsl1)
    __syncthreads();
  }
#undef OUTP_COMPUTE

#pragma unroll
  for (int ns = 0; ns < 4; ++ns) {
    const int col = n0 + wc * 64 + ns * 16 + l15;
    const float bv_ = bo[col];
#pragma unroll
    for (int ms = 0; ms < 2; ++ms) {
      const int rowb = m0 + wr * 32 + ms * 16 + quad * 4;
#pragma unroll
      for (int r = 0; r < 4; ++r) {
        pre[(size_t)(rowb + r) * 1024 + col] = f2b(acc[ms][ns][r] + bv_);
      }
    }
  }
}

// ---------------------------------------------------------------------------
// K4: out = LayerNorm(pre_bf16 + Q)*g + b -> f32. One block per row.
// ---------------------------------------------------------------------------
__global__ __launch_bounds__(256, 4) void ln_kernel(
    const ushort_t* __restrict__ pre, const float* __restrict__ Q,
    const float* __restrict__ g, const float* __restrict__ bta,
    float* __restrict__ out) {
  const int row = blockIdx.x;
  const int tid = threadIdx.x;
  const size_t base = (size_t)row * 1024 + tid * 4;
  const ushort4 p4 = *(const ushort4*)(pre + base);
  const float4 q4 = *(const float4*)(Q + base);
  float v[4] = {b2f(p4.x) + q4.x, b2f(p4.y) + q4.y,
                b2f(p4.z) + q4.z, b2f(p4.w) + q4.w};
  float s1 = v[0] + v[1] + v[2] + v[3];
  float s2 = v[0]*v[0] + v[1]*v[1] + v[2]*v[2] + v[3]*v[3];
#pragma unroll
  for (int off = 1; off < 64; off <<= 1) {
    s1 += __shfl_xor(s1, off, 64);
    s2 += __shfl_xor(s2, off, 64);
  }
  __shared__ float r1[4], r2[4];
  const int wave = tid >> 6, lane = tid & 63;
  if (lane == 0) { r1[wave] = s1; r2[wave] = s2; }
  __syncthreads();
  const float t1 = r1[0] + r1[1] + r1[2] + r1[3];
  const float t2 = r2[0] + r2[1] + r2[2] + r2[3];
  const float mu = t1 * (1.0f / 1024.0f);
  const float var = t2 * (1.0f / 1024.0f) - mu * mu;
  const float inv = rsqrtf(var + 1e-5f);
  const int c0 = tid * 4;
#pragma unroll
  for (int j = 0; j < 4; ++j) {
    const int c = c0 + j;
    out[(size_t)row * 1024 + c] = (v[j] - mu) * inv * g[c] + bta[c];
  }
}

// ---------------------------------------------------------------------------
extern "C" void kernel_launch(void* const* d_in, const int* in_sizes, int n_in,
                              void* d_out, int out_size, void* d_ws, size_t ws_size,
                              hipStream_t stream) {
  const float* Q  = (const float*)d_in[0];
  const float* K  = (const float*)d_in[1];
  const float* V  = (const float*)d_in[2];
  const float* Wq = (const float*)d_in[3];
  const float* bq = (const float*)d_in[4];
  const float* Wk = (const float*)d_in[5];
  const float* bk = (const float*)d_in[6];
  const float* Wv = (const float*)d_in[7];
  const float* bv = (const float*)d_in[8];
  const float* Wo = (const float*)d_in[9];
  const float* bo = (const float*)d_in[10];
  const float* lg = (const float*)d_in[11];
  const float* lb = (const float*)d_in[12];

  char* ws = (char*)d_ws;                       // 24 MB used
  ushort_t* qb  = (ushort_t*)(ws);                         // [B,S,D] bf16, scaled
  ushort_t* kb  = (ushort_t*)(ws + ((size_t)8  << 20));    // [B,S,D] bf16
  ushort_t* vb  = (ushort_t*)(ws + ((size_t)16 << 20));    // [B,H,dk,S] bf16
  ushort_t* pre = (ushort_t*)(ws);              // bf16, aliases qb (dead by K3)

  ushort_t* dptr  = (ushort_t*)d_out;           // u16 view of 16MB output
  ushort_t* wo_bf = dptr;                       // [0,1M) elems
  ushort_t* wq_bf = dptr + 1048576;             // [1M,2M)
  ushort_t* wk_bf = dptr + 2097152;             // [2M,3M)
  ushort_t* wv_bf = dptr + 3145728;             // [3M,4M)
  ushort_t* ctx   = dptr + 4194304;             // [4M,8M) = bytes [8MB,16MB)
  float*    out   = (float*)d_out;

  cvt4_kernel<<<dim3(512, 4), 256, 0, stream>>>(Wo, Wq, Wk, Wv, dptr);
  qkv_proj_kernel<<<dim3(256, 1, 3), 256, 0, stream>>>(Q, K, V, wq_bf, wk_bf, wv_bf,
                                                       bq, bk, bv, qb, kb, vb);
  attn_kernel<<<dim3(1024), 256, 0, stream>>>(qb, kb, vb, ctx);
  out_proj_kernel<<<dim3(512), 256, 0, stream>>>(ctx, wo_bf, bo, pre);
  ln_kernel<<<dim3(4096), 256, 0, stream>>>(pre, Q, lg, lb, out);
}